// Round 18
// baseline (239.021 us; speedup 1.0000x reference)
//
#include <hip/hip_runtime.h>
#include <hip/hip_bf16.h>
#include <stdint.h>

typedef unsigned short u16;
typedef __attribute__((ext_vector_type(4))) float f32x4;
typedef __attribute__((ext_vector_type(8))) __bf16 bf16x8;
typedef __attribute__((ext_vector_type(8))) unsigned short u16x8;
typedef __attribute__((ext_vector_type(4))) unsigned short u16x4;

#define SEQ 2048
#define HID 2048
#define HD  128

__device__ __forceinline__ float b2f(u16 v) {
    union { float f; unsigned u; } c; c.u = ((unsigned)v) << 16; return c.f;
}
__device__ __forceinline__ u16 f2b(float f) {
    union { float f; unsigned u; } c; c.f = f;
    unsigned r = c.u + 0x7fffu + ((c.u >> 16) & 1u);
    return (u16)(r >> 16);
}
__device__ __forceinline__ bf16x8 tob(u16x8 v) {
    union { u16x8 u; bf16x8 b; } c; c.u = v; return c.b;
}
__device__ __forceinline__ u16x8 ld8(const u16* p) { return *(const u16x8*)p; }

typedef const __attribute__((address_space(1))) unsigned int* gas_ptr;
typedef __attribute__((address_space(3))) unsigned int* las_ptr;
__device__ __forceinline__ void gld16(const void* g, void* l) {
    __builtin_amdgcn_global_load_lds((gas_ptr)g, (las_ptr)l, 16, 0, 0);
}

// Safe end-of-phase fence: drain DS queue (NOT vmcnt -> prefetch stays in
// flight), pin scheduling (rule #18: hipcc can defer lgkm waits past raw
// s_barrier), then barrier. Prevents queued ds_reads of buf[cur] surviving
// past the barrier while next iter's gld16 DMA overwrites it (R17 race).
#define LDS_FENCE_BARRIER()                                                   \
    do {                                                                      \
        asm volatile("s_waitcnt lgkmcnt(0)" ::: "memory");                    \
        __builtin_amdgcn_sched_barrier(0);                                    \
        __builtin_amdgcn_s_barrier();                                         \
    } while (0)

// ---------------- fused prep: RMSNorm (blocks 0..2047) + qkv-weight conv ----------------
__global__ __launch_bounds__(256) void k_prep(const float* __restrict__ x,
                                              const float* __restrict__ w,
                                              u16* __restrict__ normed,
                                              const float* __restrict__ qkvw,
                                              u16* __restrict__ qkvwb) {
    const int b = blockIdx.x, t = threadIdx.x;
    if (b < 2048) {
        const int row = b;
        const float* xr = x + (size_t)row * HID + t * 8;
        f32x4 xa = *(const f32x4*)xr;
        f32x4 xb = *(const f32x4*)(xr + 4);
        float xf[8]; float ss = 0.f;
#pragma unroll
        for (int e = 0; e < 4; ++e) { xf[e] = xa[e]; xf[e + 4] = xb[e]; }
#pragma unroll
        for (int e = 0; e < 8; ++e) ss += xf[e] * xf[e];
#pragma unroll
        for (int m = 32; m; m >>= 1) ss += __shfl_xor(ss, m);
        __shared__ float red[4];
        if ((t & 63) == 0) red[t >> 6] = ss;
        __syncthreads();
        ss = red[0] + red[1] + red[2] + red[3];
        const float sc = rsqrtf(ss * (1.0f / HID) + 1e-6f);
        f32x4 wa = *(const f32x4*)(w + t * 8);
        f32x4 wb = *(const f32x4*)(w + t * 8 + 4);
        u16x8 ov;
#pragma unroll
        for (int e = 0; e < 4; ++e) {
            ov[e] = f2b(xf[e] * sc * wa[e]);
            ov[e + 4] = f2b(xf[e + 4] * sc * wb[e]);
        }
        *(u16x8*)(normed + (size_t)row * HID + t * 8) = ov;
    } else {
        const size_t i = ((size_t)(b - 2048) * 256 + t) * 8;
        f32x4 a = *(const f32x4*)(qkvw + i);
        f32x4 bb = *(const f32x4*)(qkvw + i + 4);
        u16x8 o;
#pragma unroll
        for (int e = 0; e < 4; ++e) { o[e] = f2b(a[e]); o[e + 4] = f2b(bb[e]); }
        *(u16x8*)(qkvwb + i) = o;
    }
}

// Staging: 8 gld16 per wave per tile. LDS dest linear (rule #21); chunk
// permutation pre-applied to GLOBAL source; reads apply the same XOR.
#define STAGE_G(buf, k0)                                                      \
    do {                                                                      \
        char* a0 = (char*)&As[buf][0][0] + wave * 1024;                       \
        char* a1 = (char*)&As[buf][1][0] + wave * 1024;                       \
        char* b0 = (char*)&Bs[buf][0][0] + wave * 1024;                       \
        char* b1 = (char*)&Bs[buf][1][0] + wave * 1024;                       \
        gld16(ga + (k0), a0);                                                 \
        gld16(ga + (k0) + rowskip, a0 + 4096);                                \
        gld16(ga + (k0) + 32, a1);                                            \
        gld16(ga + (k0) + 32 + rowskip, a1 + 4096);                           \
        gld16(gb + (k0), b0);                                                 \
        gld16(gb + (k0) + rowskip, b0 + 4096);                                \
        gld16(gb + (k0) + 32, b1);                                            \
        gld16(gb + (k0) + 32 + rowskip, b1 + 4096);                           \
    } while (0)

// R5-proven K-loop + lgkm fence hardening. nk = trip count.
#define GEMM_PIPE(nk)                                                         \
    STAGE_G(0, 0);                                                            \
    for (int t = 0; t < (nk); ++t) {                                          \
        const int cur = t & 1;                                                \
        if (t + 1 < (nk)) {                                                   \
            STAGE_G(cur ^ 1, (t + 1) * 64);                                   \
            asm volatile("s_waitcnt vmcnt(8)" ::: "memory");                  \
        } else {                                                              \
            asm volatile("s_waitcnt vmcnt(0)" ::: "memory");                  \
        }                                                                     \
        __builtin_amdgcn_s_barrier();                                         \
        asm volatile("" ::: "memory");                                       \
        _Pragma("unroll")                                                     \
        for (int h = 0; h < 2; ++h) {                                         \
            const u16* as = &As[cur][h][0];                                   \
            const u16* bs = &Bs[cur][h][0];                                   \
            bf16x8 af[4], bfr[4];                                             \
            _Pragma("unroll")                                                 \
            for (int i = 0; i < 4; ++i)                                       \
                af[i] = tob(ld8(as + (wm * 64 + i * 16 + l16) * 32 + ((quad ^ sw) << 3))); \
            _Pragma("unroll")                                                 \
            for (int j = 0; j < 4; ++j)                                       \
                bfr[j] = tob(ld8(bs + (wn * 64 + j * 16 + l16) * 32 + ((quad ^ sw) << 3))); \
            _Pragma("unroll")                                                 \
            for (int i = 0; i < 4; ++i)                                       \
                _Pragma("unroll")                                             \
                for (int j = 0; j < 4; ++j)                                   \
                    acc[i][j] = __builtin_amdgcn_mfma_f32_16x16x32_bf16(af[i], bfr[j], acc[i][j], 0, 0, 0); \
        }                                                                     \
        LDS_FENCE_BARRIER();                                                  \
    }

// ------- QKV GEMM: R5 structure, scatter epilogue -------
__global__ __launch_bounds__(256) void k_gemm_qkv(const u16* __restrict__ A,
                                                  const u16* __restrict__ B,
                                                  u16* __restrict__ qraw,
                                                  u16* __restrict__ kraw,
                                                  u16* __restrict__ vtr,
                                                  int K) {
    __shared__ u16 As[2][2][128 * 32];
    __shared__ u16 Bs[2][2][128 * 32];
    const int tid = threadIdx.x;
    const int wave = tid >> 6, lane = tid & 63, quad = lane >> 4, l16 = lane & 15;
    const int wm = wave >> 1, wn = wave & 1;
    const int sw = (l16 >> 1) & 3;
    const int m0 = blockIdx.x * 128, n0 = blockIdx.y * 128;
    f32x4 acc[4][4];
#pragma unroll
    for (int i = 0; i < 4; ++i)
#pragma unroll
        for (int j = 0; j < 4; ++j) acc[i][j] = (f32x4){0.f, 0.f, 0.f, 0.f};

    const int gchunk = (tid & 3) ^ ((tid >> 3) & 3);
    const u16* ga = A + (size_t)(m0 + (tid >> 2)) * K + gchunk * 8;
    const u16* gb = B + (size_t)(n0 + (tid >> 2)) * K + gchunk * 8;
    const size_t rowskip = (size_t)64 * K;

    GEMM_PIPE(K >> 6)

#pragma unroll
    for (int i = 0; i < 4; ++i) {
        const int row = m0 + wm * 64 + i * 16 + quad * 4;
#pragma unroll
        for (int j = 0; j < 4; ++j) {
            const int col = n0 + wn * 64 + j * 16 + l16;
#pragma unroll
            for (int r = 0; r < 4; ++r) {
                const u16 val = f2b(acc[i][j][r]);
                const int s = row + r;
                if (col < 2048) {
                    const int head = col >> 7, d = col & 127;
                    qraw[((size_t)head * SEQ + s) * HD + d] = val;
                } else if (col < 3072) {
                    const int c = col - 2048, kv = c >> 7, d = c & 127;
                    kraw[((size_t)kv * SEQ + s) * HD + d] = val;
                } else {
                    const int c = col - 3072, kv = c >> 7, d = c & 127;
                    vtr[(size_t)kv * HD * SEQ + (size_t)d * SEQ + s] = val;
                }
            }
        }
    }
}

// ------- O-projection GEMM: BN=64 tiles -> 512 blocks, counted vmcnt(6), f32 out -------
__global__ __launch_bounds__(256) void k_gemm_of(const u16* __restrict__ A,
                                                 const u16* __restrict__ B,
                                                 float* __restrict__ C,
                                                 int N, int K) {
    __shared__ u16 As[2][2][128 * 32];
    __shared__ u16 Bs[2][2][64 * 32];
    const int tid = threadIdx.x;
    const int wave = tid >> 6, lane = tid & 63, quad = lane >> 4, l16 = lane & 15;
    const int wm = wave >> 1, wn = wave & 1;
    const int sw = (l16 >> 1) & 3;
    const int m0 = blockIdx.x * 128, n0 = blockIdx.y * 64;
    f32x4 acc[4][2];
#pragma unroll
    for (int i = 0; i < 4; ++i)
#pragma unroll
        for (int j = 0; j < 2; ++j) acc[i][j] = (f32x4){0.f, 0.f, 0.f, 0.f};

    const int gchunk = (tid & 3) ^ ((tid >> 3) & 3);
    const u16* ga = A + (size_t)(m0 + (tid >> 2)) * K + gchunk * 8;
    const u16* gb = B + (size_t)(n0 + (tid >> 2)) * K + gchunk * 8;
    const size_t rowskip = (size_t)64 * K;

#define STAGE_OF(buf, k0)                                                     \
    do {                                                                      \
        char* a0 = (char*)&As[buf][0][0] + wave * 1024;                       \
        char* a1 = (char*)&As[buf][1][0] + wave * 1024;                       \
        char* b0 = (char*)&Bs[buf][0][0] + wave * 1024;                       \
        char* b1 = (char*)&Bs[buf][1][0] + wave * 1024;                       \
        gld16(ga + (k0), a0);                                                 \
        gld16(ga + (k0) + rowskip, a0 + 4096);                                \
        gld16(ga + (k0) + 32, a1);                                            \
        gld16(ga + (k0) + 32 + rowskip, a1 + 4096);                           \
        gld16(gb + (k0), b0);                                                 \
        gld16(gb + (k0) + 32, b1);                                            \
    } while (0)

    STAGE_OF(0, 0);
    const int nk = K >> 6;
    for (int t = 0; t < nk; ++t) {
        const int cur = t & 1;
        if (t + 1 < nk) {
            STAGE_OF(cur ^ 1, (t + 1) * 64);
            asm volatile("s_waitcnt vmcnt(6)" ::: "memory");
        } else {
            asm volatile("s_waitcnt vmcnt(0)" ::: "memory");
        }
        __builtin_amdgcn_s_barrier();
        asm volatile("" ::: "memory");
#pragma unroll
        for (int h = 0; h < 2; ++h) {
            const u16* as = &As[cur][h][0];
            const u16* bs = &Bs[cur][h][0];
            bf16x8 af[4], bfr[2];
#pragma unroll
            for (int i = 0; i < 4; ++i)
                af[i] = tob(ld8(as + (wm * 64 + i * 16 + l16) * 32 + ((quad ^ sw) << 3)));
#pragma unroll
            for (int j = 0; j < 2; ++j)
                bfr[j] = tob(ld8(bs + (wn * 32 + j * 16 + l16) * 32 + ((quad ^ sw) << 3)));
#pragma unroll
            for (int i = 0; i < 4; ++i)
#pragma unroll
                for (int j = 0; j < 2; ++j)
                    acc[i][j] = __builtin_amdgcn_mfma_f32_16x16x32_bf16(af[i], bfr[j], acc[i][j], 0, 0, 0);
        }
        LDS_FENCE_BARRIER();
    }
#undef STAGE_OF

#pragma unroll
    for (int i = 0; i < 4; ++i) {
        const int row = m0 + wm * 64 + i * 16 + quad * 4;
#pragma unroll
        for (int j = 0; j < 2; ++j) {
            const int col = n0 + wn * 32 + j * 16 + l16;
#pragma unroll
            for (int r = 0; r < 4; ++r)
                C[(size_t)(row + r) * N + col] = acc[i][j][r];
        }
    }
}

// ---------------- fused: in-place RoPE + per-head RMSNorm (y<6) + ow conv (y==6) ----------------
__global__ __launch_bounds__(256) void k_ropeconv(const int* __restrict__ pos,
                                                  const float* __restrict__ qw,
                                                  const float* __restrict__ kw,
                                                  u16* __restrict__ qraw,
                                                  u16* __restrict__ kraw,
                                                  const float* __restrict__ ow,
                                                  u16* __restrict__ owb) {
    if (blockIdx.y < 6) {
        const int s = blockIdx.x;
        const int h = blockIdx.y * 4 + (threadIdx.x >> 6);
        const int d = threadIdx.x & 63;
        const bool isq = h < 16;
        u16* row = isq ? (qraw + ((size_t)h * SEQ + s) * HD)
                       : (kraw + ((size_t)(h - 16) * SEQ + s) * HD);
        const float x1 = b2f(row[d]), x2 = b2f(row[d + 64]);
        const float p = (float)pos[s];
        const float inv = exp2f(-(float)d * (2.0f / 128.0f) * 13.287712379549449f);
        const float fr = p * inv;
        const float c = cosf(fr), sn = sinf(fr);
        const float o1 = x1 * c - x2 * sn;
        const float o2 = x2 * c + x1 * sn;
        float ss = o1 * o1 + o2 * o2;
#pragma unroll
        for (int m = 32; m; m >>= 1) ss += __shfl_xor(ss, m);
        const float sc = rsqrtf(ss * (1.0f / HD) + 1e-6f);
        const float* w = isq ? qw : kw;
        row[d] = f2b(o1 * sc * w[d]);
        row[d + 64] = f2b(o2 * sc * w[d + 64]);
    } else {
        const size_t i = ((size_t)blockIdx.x * 256 + threadIdx.x) * 8;
        f32x4 a = *(const f32x4*)(ow + i);
        f32x4 b = *(const f32x4*)(ow + i + 4);
        u16x8 o;
#pragma unroll
        for (int e = 0; e < 4; ++e) { o[e] = f2b(a[e]); o[e + 4] = f2b(b[e]); }
        *(u16x8*)(owb + i) = o;
    }
}

// ---------------- causal flash attention: QBLK=128, slot-permuted P, gld16 dbuf staging ----------------
// K/V staged via global_load_lds double buffers, counted vmcnt(8). LDS dest
// linear (rule #21); rho-permutation + chunk XOR folded into the GLOBAL source:
//   K row u holds global row rho_inv(u)=(u&35)|((u&16)>>2)|((u&8)<<1)|((u&4)<<1),
//   slot s holds chunk s^(u&7); V row vrow slot s holds chunk s^(vrow&7).
// Slot permutation: QK^T slot (j,quad,r) holds P at kpos 32(j>>1)+8q+4(j&1)+r ==
// PV A-fragment element -> in-lane pack, no P LDS. End-of-iter LDS_FENCE_BARRIER
// drains lgkm (not vmcnt) before buffers are overwritten (fixes R17 replay race).
__global__ __launch_bounds__(256, 2) void k_attn(const u16* __restrict__ qh,
                                                 const u16* __restrict__ kh,
                                                 const u16* __restrict__ vt,
                                                 u16* __restrict__ out,
                                                 u16* __restrict__ po,
                                                 float* __restrict__ pl) {
    const int tid = threadIdx.x;
    const int wave = tid >> 6, lane = tid & 63, quad = lane >> 4, l16 = lane & 15;
    const int head = blockIdx.y;
    const int b = blockIdx.x;            // 0..32
    int Q, part, np;
    if (b < 5)       { Q = b;                    part = 0;            np = 1; }
    else if (b < 15) { Q = 5 + ((b - 5) >> 1);   part = (b - 5) & 1;  np = 2; }
    else             { Q = 10 + (b - 15) / 3;    part = (b - 15) % 3; np = 3; }
    const int kvh = head >> 1;
    const int q0 = Q * 128;
    const int ntiles = 2 * Q + 2;        // causal k-tiles of 64 covering rows q0..q0+127

    __shared__ u16 Ks[2][64 * 128];
    __shared__ u16 Vts[2][128 * 64];

    const u16* qbase = qh + ((size_t)head * SEQ + q0 + wave * 32) * HD;
    bf16x8 aq[2][4];
#pragma unroll
    for (int u = 0; u < 2; ++u)
#pragma unroll
        for (int kk = 0; kk < 4; ++kk)
            aq[u][kk] = tob(ld8(qbase + (u * 16 + l16) * HD + kk * 32 + quad * 8));

    f32x4 acco[2][8];
#pragma unroll
    for (int u = 0; u < 2; ++u)
#pragma unroll
        for (int j = 0; j < 8; ++j) acco[u][j] = (f32x4){0.f, 0.f, 0.f, 0.f};
    float lsum[2] = {0.f, 0.f};

    const float sc = 0.08838834764831845f; // 1/sqrt(128)
    const u16* kbase = kh + (size_t)kvh * SEQ * HD;
    const u16* vbase = vt + (size_t)kvh * HD * SEQ;
    const int qrow0 = q0 + wave * 32 + l16; // u=0 row; u=1 adds 16

    // per-lane global sources for gld16 staging (inverse-permuted/swizzled)
    const u16* kgsrc[4];
    const u16* vgsrc[4];
#pragma unroll
    for (int i = 0; i < 4; ++i) {
        const int u = wave * 16 + i * 4 + ((tid & 63) >> 4);   // permuted LDS row
        const int kp = (u & 35) | ((u & 16) >> 2) | ((u & 8) << 1) | ((u & 4) << 1); // rho_inv
        const int c = (tid & 15) ^ (u & 7);
        kgsrc[i] = kbase + (size_t)kp * 128 + c * 8;
        const int vrow = wave * 32 + i * 8 + ((tid & 63) >> 3);
        const int cv = (tid & 7) ^ (vrow & 7);
        vgsrc[i] = vbase + (size_t)vrow * SEQ + cv * 8;
    }

#define STAGE_ATT(buf, ktile)                                                 \
    do {                                                                      \
        const size_t ko = (size_t)(ktile) * 64;                               \
        char* kb = (char*)&Ks[buf][0] + wave * 4096;                          \
        char* vb = (char*)&Vts[buf][0] + wave * 4096;                         \
        _Pragma("unroll")                                                     \
        for (int i = 0; i < 4; ++i) gld16(kgsrc[i] + ko * 128, kb + i * 1024);\
        _Pragma("unroll")                                                     \
        for (int i = 0; i < 4; ++i) gld16(vgsrc[i] + ko, vb + i * 1024);      \
    } while (0)

    STAGE_ATT(0, part);
    int it = 0;
    for (int kt = part; kt < ntiles; kt += np, ++it) {
        const int cur = it & 1;
        const bool havenext = (kt + np) < ntiles;
        if (havenext) {
            STAGE_ATT(cur ^ 1, kt + np);
            asm volatile("s_waitcnt vmcnt(8)" ::: "memory");
        } else {
            asm volatile("s_waitcnt vmcnt(0)" ::: "memory");
        }
        __builtin_amdgcn_s_barrier();
        asm volatile("" ::: "memory");

        const u16* ksc = &Ks[cur][0];
        const u16* vsc = &Vts[cur][0];

        // S^T = K Q^T for both 16-row slices (bk loaded once, used twice)
        f32x4 accs[2][4];
#pragma unroll
        for (int u = 0; u < 2; ++u)
#pragma unroll
            for (int j = 0; j < 4; ++j) accs[u][j] = (f32x4){0.f, 0.f, 0.f, 0.f};
#pragma unroll
        for (int kk = 0; kk < 4; ++kk) {
#pragma unroll
            for (int j = 0; j < 4; ++j) {
                const int krow = j * 16 + l16;
                const bf16x8 bk = tob(ld8(ksc + krow * 128 + (((kk * 4 + quad) ^ (krow & 7)) << 3)));
                accs[0][j] = __builtin_amdgcn_mfma_f32_16x16x32_bf16(bk, aq[0][kk], accs[0][j], 0, 0, 0);
                accs[1][j] = __builtin_amdgcn_mfma_f32_16x16x32_bf16(bk, aq[1][kk], accs[1][j], 0, 0, 0);
            }
        }

        // P = exp(s*sc) (M=0), causal mask; pack PV A-fragments IN-LANE per slice
        const int k0 = kt * 64;
        u16x8 apk[2][2];
#pragma unroll
        for (int u = 0; u < 2; ++u) {
            const int qrg = qrow0 + u * 16;
#pragma unroll
            for (int j = 0; j < 4; ++j) {
#pragma unroll
                for (int r = 0; r < 4; ++r) {
                    const int kpos = k0 + ((j >> 1) << 5) + (quad << 3) + ((j & 1) << 2) + r;
                    const float pv = (kpos > qrg) ? 0.f : __expf(accs[u][j][r] * sc);
                    lsum[u] += pv;
                    apk[u][j >> 1][((j & 1) << 2) + r] = f2b(pv);
                }
            }
        }

        // O += P V (ap lane-local; bv loaded once, used twice)
#pragma unroll
        for (int kk = 0; kk < 2; ++kk) {
            const bf16x8 ap0 = tob(apk[0][kk]);
            const bf16x8 ap1 = tob(apk[1][kk]);
#pragma unroll
            for (int j = 0; j < 8; ++j) {
                const int vrow = j * 16 + l16;
                const bf16x8 bv = tob(ld8(vsc + vrow * 64 + (((kk * 4 + quad) ^ (vrow & 7)) << 3)));
                acco[0][j] = __builtin_amdgcn_mfma_f32_16x16x32_bf16(ap0, bv, acco[0][j], 0, 0, 0);
                acco[1][j] = __builtin_amdgcn_mfma_f32_16x16x32_bf16(ap1, bv, acco[1][j], 0, 0, 0);
            }
        }

        LDS_FENCE_BARRIER(); // DS queue drained before next iter's gld16 overwrites
    }
#undef STAGE_ATT

    // per-slice l reduction + output
#pragma unroll
    for (int u = 0; u < 2; ++u) {
        float v = lsum[u];
        v += __shfl_xor(v, 16);
        v += __shfl_xor(v, 32);
        const int rowb = q0 + wave * 32 + u * 16 + quad * 4;

        if (np == 1) {
            f32x4 il;
#pragma unroll
            for (int r = 0; r < 4; ++r) il[r] = 1.0f / __shfl(v, quad * 4 + r);
#pragma unroll
            for (int j = 0; j < 8; ++j) {
                const int col = head * HD + j * 16 + l16;
#pragma unroll
                for (int r = 0; r < 4; ++r)
                    out[(size_t)(rowb + r) * 2048 + col] = f2b(acco[u][j][r] * il[r]);
            }
        } else {
            u16* pob = po + (size_t)part * SEQ * 2048;
            float* plb = pl + (size_t)part * 16 * SEQ;
            if (lane < 16) plb[head * SEQ + q0 + wave * 32 + u * 16 + l16] = v;
#pragma unroll
            for (int j = 0; j < 8; ++j) {
                const int col = head * HD + j * 16 + l16;
#pragma unroll
                for (int r = 0; r < 4; ++r)
                    pob[(size_t)(rowb + r) * 2048 + col] = f2b(acco[u][j][r]);
            }
        }
    }
}

// ---------------- split-K merge + normalize for rows s >= 640 ----------------
__global__ __launch_bounds__(256) void k_amerge(const u16* __restrict__ po,
                                                const float* __restrict__ pl,
                                                u16* __restrict__ out) {
    const int s = blockIdx.x + 640;
    const int Q = s >> 7;
    const int np = (Q >= 10) ? 3 : 2;
    const int t = threadIdx.x;
    const int head = t >> 4;

    float l = 0.f;
#pragma unroll
    for (int p = 0; p < 3; ++p)
        if (p < np) l += pl[(size_t)p * 16 * SEQ + head * SEQ + s];
    const float il = 1.0f / l;

    float o[8] = {0.f, 0.f, 0.f, 0.f, 0.f, 0.f, 0.f, 0.f};
#pragma unroll
    for (int p = 0; p < 3; ++p) {
        if (p < np) {
            const u16x8 vv = ld8(po + (size_t)p * SEQ * 2048 + (size_t)s * 2048 + t * 8);
#pragma unroll
            for (int e = 0; e < 8; ++e) o[e] += b2f(vv[e]);
        }
    }
    u16x8 ov;
#pragma unroll
    for (int e = 0; e < 8; ++e) ov[e] = f2b(o[e] * il);
    *(u16x8*)(out + (size_t)s * 2048 + t * 8) = ov;
}

extern "C" void kernel_launch(void* const* d_in, const int* in_sizes, int n_in,
                              void* d_out, int out_size, void* d_ws, size_t ws_size,
                              hipStream_t stream) {
    const int*   positions = (const int*)d_in[0];
    const float* hidden   = (const float*)d_in[1];
    const float* lnw      = (const float*)d_in[2];
    const float* qkvw     = (const float*)d_in[3];
    const float* qnw      = (const float*)d_in[4];
    const float* knw      = (const float*)d_in[5];
    const float* ow       = (const float*)d_in[6];
    float* outp = (float*)d_out;

    char* ws = (char*)d_ws;
    const size_t MB = 1024ull * 1024ull;
    u16* normed = (u16*)(ws + 0 * MB);   // [S][2048] bf16 — dead after QKV gemm
    u16* qraw   = (u16*)(ws + 8 * MB);   // [16][S][128] — dead after attn
    u16* kraw   = (u16*)(ws + 16 * MB);  // [8][S][128]  — dead after attn
    u16* vtr    = (u16*)(ws + 20 * MB);  // [8][128][S]  — dead after attn
    u16* qkvwb  = (u16*)(ws + 24 * MB);  // [4096][2048] bf16 — dead after QKV gemm
    u16* owb    = (u16*)(ws + 0 * MB);   // [2048][2048] bf16, overwrites normed (after qkv)
    u16* attno  = (u16*)(ws + 24 * MB);  // [S][2048] bf16, overwrites qkvwb head
    u16* po     = (u16*)(ws + 32 * MB);  // [3][S][2048] bf16 attn partials (24MB)
    float* pl   = (float*)(ws + 56 * MB);// [3][16][S] f32 attn l-partials

    k_prep    <<<6144, 256, 0, stream>>>(hidden, lnw, normed, qkvw, qkvwb);
    k_gemm_qkv<<<dim3(16, 32), 256, 0, stream>>>(normed, qkvwb, qraw, kraw, vtr, HID);
    k_ropeconv<<<dim3(SEQ, 7), 256, 0, stream>>>(positions, qnw, knw, qraw, kraw, ow, owb);
    k_attn    <<<dim3(33, 16), 256, 0, stream>>>(qraw, kraw, vtr, attno, po, pl);
    k_amerge  <<<1408, 256, 0, stream>>>(po, pl, attno);
    k_gemm_of <<<dim3(16, 32), 256, 0, stream>>>(attno, owb, outp, HID, HID);
}